// Round 2
// baseline (40621.979 us; speedup 1.0000x reference)
//
#include <hip/hip_runtime.h>
#include <hip/hip_bf16.h>

// HeteroGATv2: 3 node types x 50000 nodes, 7 edge types x 800000 edges,
// 2 GATv2 layers (H=64), softmax head (4 classes) on node type 0.
// Dtype-adaptive: a detector kernel decides at runtime whether the float
// tensors are bf16 or f32 (flag in workspace); all float loads and the
// output write go through that flag. Deterministic: same inputs -> same flag.

#define N_NODES 50000
#define NEDGE   800000
#define HDIM    64
#define DIN     32

typedef __hip_bfloat16 bf16;

__device__ __forceinline__ float ldf(const void* p, size_t i, int bf) {
    return bf ? __bfloat162float(((const bf16*)p)[i]) : ((const float*)p)[i];
}

// monotone float<->uint mapping for atomicMax on floats
__device__ __forceinline__ unsigned fkey(float f) {
    unsigned u = __float_as_uint(f);
    return (u & 0x80000000u) ? ~u : (u | 0x80000000u);
}
__device__ __forceinline__ float kinv(unsigned k) {
    unsigned u = (k & 0x80000000u) ? (k & 0x7fffffffu) : ~k;
    return __uint_as_float(u);
}

// flag[0] = 1 if x is bf16, 0 if f32. Reading f32 data as bf16 makes half the
// 16-bit slots (the mantissa halves) have uniform-random exponents; true bf16
// N(0,1) data has exponents confined to ~[114,133].
__global__ void detect_kernel(const unsigned short* __restrict__ x, int* __restrict__ flag)
{
    __shared__ int sbad[256];
    int bad = 0;
    for (int i = threadIdx.x; i < 4096; i += 256) {
        unsigned short u = x[i];
        int ex = (u >> 7) & 0xff;
        bool zero = (u & 0x7fffu) == 0;
        if (!zero && (ex < 80 || ex > 140)) bad++;
    }
    sbad[threadIdx.x] = bad;
    __syncthreads();
    for (int s = 128; s > 0; s >>= 1) {
        if (threadIdx.x < s) sbad[threadIdx.x] += sbad[threadIdx.x + s];
        __syncthreads();
    }
    if (threadIdx.x == 0) flag[0] = (sbad[0] < 64) ? 1 : 0;
}

// out[node][h] = b[h] + sum_d feat[node][d] * W[d][h]; feat dtype per flag
// (dual pointers fb/ff are the same tensor offset computed per-dtype).
__global__ __launch_bounds__(256) void lin_d32_kernel(
    const void* fb, const void* ff, const void* wb, const void* wf,
    const void* bb, const void* bfp, const int* __restrict__ flag,
    float* __restrict__ out, int n)
{
    __shared__ float sW[DIN * HDIM];
    __shared__ float sb[HDIM];
    int bf = flag[0];
    const void* W = bf ? wb : wf;
    const void* b = bf ? bb : bfp;
    const void* feat = bf ? fb : ff;
    int tid = threadIdx.x;
    for (int k = tid; k < DIN * HDIM; k += 256) sW[k] = ldf(W, k, bf);
    if (tid < HDIM) sb[tid] = ldf(b, tid, bf);
    __syncthreads();
    int node = blockIdx.x * 4 + (tid >> 6);
    if (node >= n) return;
    int h = tid & 63;
    float acc = sb[h];
    #pragma unroll
    for (int d = 0; d < DIN; ++d)
        acc += ldf(feat, (size_t)node * DIN + d, bf) * sW[d * HDIM + h];
    out[(size_t)node * HDIM + h] = acc;
}

// layer-1 variant: feat is always f32 (hidden state in workspace)
__global__ __launch_bounds__(256) void lin_d64_kernel(
    const float* __restrict__ feat, const void* wb, const void* wf,
    const void* bb, const void* bfp, const int* __restrict__ flag,
    float* __restrict__ out, int n)
{
    __shared__ float sW[HDIM * HDIM];
    __shared__ float sb[HDIM];
    int bf = flag[0];
    const void* W = bf ? wb : wf;
    const void* b = bf ? bb : bfp;
    int tid = threadIdx.x;
    for (int k = tid; k < HDIM * HDIM; k += 256) sW[k] = ldf(W, k, bf);
    if (tid < HDIM) sb[tid] = ldf(b, tid, bf);
    __syncthreads();
    int node = blockIdx.x * 4 + (tid >> 6);
    if (node >= n) return;
    int h = tid & 63;
    float acc = sb[h];
    const float4* f4 = (const float4*)(feat + (size_t)node * HDIM);
    #pragma unroll
    for (int k = 0; k < 16; ++k) {
        float4 a = f4[k];
        acc += a.x * sW[(4*k+0) * HDIM + h] + a.y * sW[(4*k+1) * HDIM + h]
             + a.z * sW[(4*k+2) * HDIM + h] + a.w * sW[(4*k+3) * HDIM + h];
    }
    out[(size_t)node * HDIM + h] = acc;
}

// e[i] = att . leaky_relu(xl[src] + xr[dst]); atomicMax into mkey[dst]
__global__ __launch_bounds__(256) void attnA_kernel(
    const int* __restrict__ eidx, const float* __restrict__ xl,
    const float* __restrict__ xr, const void* ab, const void* af,
    const int* __restrict__ flag, float* __restrict__ ebuf,
    unsigned* __restrict__ mkey)
{
    __shared__ float satt[HDIM];
    int bf = flag[0];
    const void* att = bf ? ab : af;
    int tid = threadIdx.x;
    if (tid < HDIM) satt[tid] = ldf(att, tid, bf);
    __syncthreads();
    int i = blockIdx.x * 256 + tid;
    if (i >= NEDGE) return;
    int s = eidx[i], d = eidx[NEDGE + i];
    const float4* pa = (const float4*)(xl + (size_t)s * HDIM);
    const float4* pb = (const float4*)(xr + (size_t)d * HDIM);
    float acc = 0.f;
    #pragma unroll
    for (int k = 0; k < 16; ++k) {
        float4 a = pa[k], b2 = pb[k];
        float v;
        v = a.x + b2.x; v = v > 0.f ? v : 0.2f * v; acc += satt[4*k+0] * v;
        v = a.y + b2.y; v = v > 0.f ? v : 0.2f * v; acc += satt[4*k+1] * v;
        v = a.z + b2.z; v = v > 0.f ? v : 0.2f * v; acc += satt[4*k+2] * v;
        v = a.w + b2.w; v = v > 0.f ? v : 0.2f * v; acc += satt[4*k+3] * v;
    }
    ebuf[i] = acc;
    atomicMax(&mkey[d], fkey(acc));
}

__global__ __launch_bounds__(256) void attnB1_kernel(
    const int* __restrict__ eidx, float* __restrict__ ebuf,
    const unsigned* __restrict__ mkey, float* __restrict__ sden)
{
    int i = blockIdx.x * 256 + threadIdx.x;
    if (i >= NEDGE) return;
    int d = eidx[NEDGE + i];
    float ex = __expf(ebuf[i] - kinv(mkey[d]));
    ebuf[i] = ex;
    atomicAdd(&sden[d], ex);
}

__global__ __launch_bounds__(256) void attnB2_kernel(
    const int* __restrict__ eidx, const float* __restrict__ ebuf,
    const float* __restrict__ xl, const float* __restrict__ sden,
    float* __restrict__ hn)
{
    int i = blockIdx.x * 256 + threadIdx.x;
    if (i >= NEDGE) return;
    int s = eidx[i], d = eidx[NEDGE + i];
    float w = ebuf[i] / (sden[d] + 1e-16f);
    const float4* pa = (const float4*)(xl + (size_t)s * HDIM);
    float* o = hn + (size_t)d * HDIM;
    #pragma unroll
    for (int k = 0; k < 16; ++k) {
        float4 a = pa[k];
        atomicAdd(o + 4*k + 0, w * a.x);
        atomicAdd(o + 4*k + 1, w * a.y);
        atomicAdd(o + 4*k + 2, w * a.z);
        atomicAdd(o + 4*k + 3, w * a.w);
    }
}

// per-node-type summed bias (HeteroConv 'sum': one bias per incoming edge type)
__global__ void bsum_kernel(const void* __restrict__ bias, const int* __restrict__ flag,
                            float* __restrict__ bsum)
{
    int bf = flag[0];
    int idx = threadIdx.x;  // 192 = 3*64
    if (idx >= 192) return;
    int nt = idx >> 6, h = idx & 63;
    float v;
    if (nt == 0)      v = ldf(bias, 0*64+h, bf) + ldf(bias, 1*64+h, bf) + ldf(bias, 4*64+h, bf);
    else if (nt == 1) v = ldf(bias, 2*64+h, bf) + ldf(bias, 5*64+h, bf);
    else              v = ldf(bias, 3*64+h, bf) + ldf(bias, 6*64+h, bf);
    bsum[idx] = v;
}

__global__ __launch_bounds__(256) void relu_kernel(
    const float* __restrict__ hn, const float* __restrict__ bsum,
    float* __restrict__ h)
{
    size_t idx = (size_t)blockIdx.x * 256 + threadIdx.x;
    if (idx >= (size_t)3 * N_NODES * HDIM) return;
    int nt = (int)(idx / ((size_t)N_NODES * HDIM));
    int hh = (int)(idx & 63);
    float v = hn[idx] + bsum[nt * 64 + hh];
    h[idx] = v > 0.f ? v : 0.f;
}

// logits = h0 @ Wout + bout -> softmax -> out (dtype per flag)
__global__ __launch_bounds__(256) void head_kernel(
    const float* __restrict__ h0, const void* __restrict__ Wout,
    const void* __restrict__ bout, const int* __restrict__ flag,
    void* __restrict__ out)
{
    __shared__ float sW[64 * 4];
    __shared__ float sb[4];
    int bf = flag[0];
    int tid = threadIdx.x;
    sW[tid] = ldf(Wout, tid, bf);
    if (tid < 4) sb[tid] = ldf(bout, tid, bf);
    __syncthreads();
    int i = blockIdx.x * 256 + tid;
    if (i >= N_NODES) return;
    float l0 = sb[0], l1 = sb[1], l2 = sb[2], l3 = sb[3];
    const float4* p = (const float4*)(h0 + (size_t)i * HDIM);
    #pragma unroll
    for (int k = 0; k < 16; ++k) {
        float4 a = p[k];
        int d = 4 * k;
        l0 += a.x * sW[d*4+0] + a.y * sW[(d+1)*4+0] + a.z * sW[(d+2)*4+0] + a.w * sW[(d+3)*4+0];
        l1 += a.x * sW[d*4+1] + a.y * sW[(d+1)*4+1] + a.z * sW[(d+2)*4+1] + a.w * sW[(d+3)*4+1];
        l2 += a.x * sW[d*4+2] + a.y * sW[(d+1)*4+2] + a.z * sW[(d+2)*4+2] + a.w * sW[(d+3)*4+2];
        l3 += a.x * sW[d*4+3] + a.y * sW[(d+1)*4+3] + a.z * sW[(d+2)*4+3] + a.w * sW[(d+3)*4+3];
    }
    float m = fmaxf(fmaxf(l0, l1), fmaxf(l2, l3));
    float e0 = __expf(l0 - m), e1 = __expf(l1 - m), e2 = __expf(l2 - m), e3 = __expf(l3 - m);
    float inv = 1.f / (e0 + e1 + e2 + e3);
    if (bf) {
        bf16* o = (bf16*)out;
        o[(size_t)4*i + 0] = __float2bfloat16(e0 * inv);
        o[(size_t)4*i + 1] = __float2bfloat16(e1 * inv);
        o[(size_t)4*i + 2] = __float2bfloat16(e2 * inv);
        o[(size_t)4*i + 3] = __float2bfloat16(e3 * inv);
    } else {
        float* o = (float*)out;
        o[(size_t)4*i + 0] = e0 * inv;
        o[(size_t)4*i + 1] = e1 * inv;
        o[(size_t)4*i + 2] = e2 * inv;
        o[(size_t)4*i + 3] = e3 * inv;
    }
}

struct P2 { const void* b; const void* f; };
static inline P2 off2(const void* base, size_t elem) {
    P2 r;
    r.b = (const void*)((const bf16*)base + elem);
    r.f = (const void*)((const float*)base + elem);
    return r;
}

extern "C" void kernel_launch(void* const* d_in, const int* in_sizes, int n_in,
                              void* d_out, int out_size, void* d_ws, size_t ws_size,
                              hipStream_t stream)
{
    const void* x     = d_in[0];
    const int*  edges = (const int*)d_in[1];
    const void* Wl0 = d_in[2];
    const void* Wr0 = d_in[3];
    const void* bl0 = d_in[4];
    const void* br0 = d_in[5];
    const void* att0 = d_in[6];
    const void* bias0 = d_in[7];
    const void* Wl1 = d_in[8];
    const void* Wr1 = d_in[9];
    const void* bl1 = d_in[10];
    const void* br1 = d_in[11];
    const void* att1 = d_in[12];
    const void* bias1 = d_in[13];
    const void* Wout = d_in[14];
    const void* bout = d_in[15];

    const int SRCt[7] = {0, 1, 1, 1, 2, 2, 2};
    const int DSTt[7] = {0, 0, 1, 2, 0, 1, 2};

    // workspace layout (f32 elements): ~106 MB
    float* h3  = (float*)d_ws;                                  // 3*N*H
    float* hn3 = h3 + (size_t)3 * N_NODES * HDIM;               // 3*N*H
    float* xl  = hn3 + (size_t)3 * N_NODES * HDIM;              // N*H
    float* xr  = xl + (size_t)N_NODES * HDIM;                   // N*H
    float* ebuf = xr + (size_t)N_NODES * HDIM;                  // E
    unsigned* mkey = (unsigned*)(ebuf + NEDGE);                 // N
    float* sden = (float*)(mkey + N_NODES);                     // N
    float* bsum = sden + N_NODES;                               // 192
    int* flag = (int*)(bsum + 192);                             // 1

    dim3 blk(256);
    int gLin = (N_NODES + 3) / 4;
    int gE   = (NEDGE + 255) / 256;
    int gRelu = (int)(((size_t)3 * N_NODES * HDIM + 255) / 256);
    int gHead = (N_NODES + 255) / 256;

    detect_kernel<<<1, 256, 0, stream>>>((const unsigned short*)x, flag);

    // ---------------- layer 0 (D_IN=32) ----------------
    hipMemsetAsync(hn3, 0, (size_t)3 * N_NODES * HDIM * sizeof(float), stream);
    bsum_kernel<<<1, 192, 0, stream>>>(bias0, flag, bsum);
    for (int t = 0; t < 7; ++t) {
        P2 fs = off2(x, (size_t)SRCt[t] * N_NODES * DIN);
        P2 fd = off2(x, (size_t)DSTt[t] * N_NODES * DIN);
        P2 wl = off2(Wl0, (size_t)t * DIN * HDIM);
        P2 wr = off2(Wr0, (size_t)t * DIN * HDIM);
        P2 bl = off2(bl0, (size_t)t * HDIM);
        P2 br = off2(br0, (size_t)t * HDIM);
        P2 at = off2(att0, (size_t)t * HDIM);
        lin_d32_kernel<<<gLin, blk, 0, stream>>>(fs.b, fs.f, wl.b, wl.f, bl.b, bl.f, flag, xl, N_NODES);
        lin_d32_kernel<<<gLin, blk, 0, stream>>>(fd.b, fd.f, wr.b, wr.f, br.b, br.f, flag, xr, N_NODES);
        hipMemsetAsync(mkey, 0, N_NODES * sizeof(unsigned), stream);
        hipMemsetAsync(sden, 0, N_NODES * sizeof(float), stream);
        const int* ei = edges + (size_t)t * 2 * NEDGE;
        attnA_kernel<<<gE, blk, 0, stream>>>(ei, xl, xr, at.b, at.f, flag, ebuf, mkey);
        attnB1_kernel<<<gE, blk, 0, stream>>>(ei, ebuf, mkey, sden);
        attnB2_kernel<<<gE, blk, 0, stream>>>(ei, ebuf, xl, sden, hn3 + (size_t)DSTt[t] * N_NODES * HDIM);
    }
    relu_kernel<<<gRelu, blk, 0, stream>>>(hn3, bsum, h3);

    // ---------------- layer 1 (D=64, f32 hidden state) ----------------
    hipMemsetAsync(hn3, 0, (size_t)3 * N_NODES * HDIM * sizeof(float), stream);
    bsum_kernel<<<1, 192, 0, stream>>>(bias1, flag, bsum);
    for (int t = 0; t < 7; ++t) {
        P2 wl = off2(Wl1, (size_t)t * HDIM * HDIM);
        P2 wr = off2(Wr1, (size_t)t * HDIM * HDIM);
        P2 bl = off2(bl1, (size_t)t * HDIM);
        P2 br = off2(br1, (size_t)t * HDIM);
        P2 at = off2(att1, (size_t)t * HDIM);
        lin_d64_kernel<<<gLin, blk, 0, stream>>>(h3 + (size_t)SRCt[t] * N_NODES * HDIM,
                                                 wl.b, wl.f, bl.b, bl.f, flag, xl, N_NODES);
        lin_d64_kernel<<<gLin, blk, 0, stream>>>(h3 + (size_t)DSTt[t] * N_NODES * HDIM,
                                                 wr.b, wr.f, br.b, br.f, flag, xr, N_NODES);
        hipMemsetAsync(mkey, 0, N_NODES * sizeof(unsigned), stream);
        hipMemsetAsync(sden, 0, N_NODES * sizeof(float), stream);
        const int* ei = edges + (size_t)t * 2 * NEDGE;
        attnA_kernel<<<gE, blk, 0, stream>>>(ei, xl, xr, at.b, at.f, flag, ebuf, mkey);
        attnB1_kernel<<<gE, blk, 0, stream>>>(ei, ebuf, mkey, sden);
        attnB2_kernel<<<gE, blk, 0, stream>>>(ei, ebuf, xl, sden, hn3 + (size_t)DSTt[t] * N_NODES * HDIM);
    }
    relu_kernel<<<gRelu, blk, 0, stream>>>(hn3, bsum, h3);

    // ---------------- output head ----------------
    head_kernel<<<gHead, blk, 0, stream>>>(h3, Wout, bout, flag, d_out);
}

// Round 3
// 5618.243 us; speedup vs baseline: 7.2304x; 7.2304x over previous
//
#include <hip/hip_runtime.h>
#include <hip/hip_bf16.h>

// HeteroGATv2: 3 node types x 50000 nodes, 7 edge types x 800000 edges,
// 2 GATv2 layers (H=64), softmax head (4 classes) on node type 0.
//
// R3: replace the atomic-scatter attention (attnB2 was 93% of runtime,
// 1.6 GB HBM writes per dispatch from 51.2M f32 atomics) with a per-edge-type
// CSR build + one wave per destination node doing chunked online softmax in
// registers and a single non-atomic coalesced output write.
//
// Dtype-adaptive (proven in R2): detector decides bf16 vs f32 for all float
// inputs; flag in workspace steers loads and the output write.

#define N_NODES 50000
#define NEDGE   800000
#define HDIM    64
#define DIN     32

typedef __hip_bfloat16 bf16;

__device__ __forceinline__ float ldf(const void* p, size_t i, int bf) {
    return bf ? __bfloat162float(((const bf16*)p)[i]) : ((const float*)p)[i];
}

// flag[0] = 1 if x is bf16, 0 if f32.
__global__ void detect_kernel(const unsigned short* __restrict__ x, int* __restrict__ flag)
{
    __shared__ int sbad[256];
    int bad = 0;
    for (int i = threadIdx.x; i < 4096; i += 256) {
        unsigned short u = x[i];
        int ex = (u >> 7) & 0xff;
        bool zero = (u & 0x7fffu) == 0;
        if (!zero && (ex < 80 || ex > 140)) bad++;
    }
    sbad[threadIdx.x] = bad;
    __syncthreads();
    for (int s = 128; s > 0; s >>= 1) {
        if (threadIdx.x < s) sbad[threadIdx.x] += sbad[threadIdx.x + s];
        __syncthreads();
    }
    if (threadIdx.x == 0) flag[0] = (sbad[0] < 64) ? 1 : 0;
}

// ---------------- CSR build (per layer, per edge type) ----------------

__global__ __launch_bounds__(256) void hist_kernel(const int* __restrict__ dst,
                                                   int* __restrict__ cnt)
{
    int i = blockIdx.x * 256 + threadIdx.x;
    if (i < NEDGE) atomicAdd(&cnt[dst[i]], 1);
}

// single-block exclusive scan of cnt[0..N) -> rowptr[0..N]; also cursor = rowptr
__global__ __launch_bounds__(1024) void scan_kernel(const int* __restrict__ cnt,
                                                    int* __restrict__ rowptr,
                                                    int* __restrict__ cursor)
{
    __shared__ int part[1024];
    const int ITEMS = (N_NODES + 1023) / 1024;  // 49
    int t = threadIdx.x;
    int base = t * ITEMS;
    int loc = 0;
    for (int k = 0; k < ITEMS; ++k) {
        int i = base + k;
        if (i < N_NODES) loc += cnt[i];
    }
    part[t] = loc;
    __syncthreads();
    for (int off = 1; off < 1024; off <<= 1) {
        int v = (t >= off) ? part[t - off] : 0;
        __syncthreads();
        part[t] += v;
        __syncthreads();
    }
    int pre = (t == 0) ? 0 : part[t - 1];
    for (int k = 0; k < ITEMS; ++k) {
        int i = base + k;
        if (i < N_NODES) {
            rowptr[i] = pre;
            cursor[i] = pre;
            pre += cnt[i];
        }
    }
    if (t == 1023) rowptr[N_NODES] = part[1023];
}

__global__ __launch_bounds__(256) void scatter_kernel(const int* __restrict__ ei,
                                                      int* __restrict__ cursor,
                                                      int* __restrict__ col_src)
{
    int i = blockIdx.x * 256 + threadIdx.x;
    if (i >= NEDGE) return;
    int s = ei[i], d = ei[NEDGE + i];
    int pos = atomicAdd(&cursor[d], 1);
    col_src[pos] = s;
}

// ---------------- linear transforms ----------------

__global__ __launch_bounds__(256) void lin_d32_kernel(
    const void* fb, const void* ff, const void* wb, const void* wf,
    const void* bb, const void* bfp, const int* __restrict__ flag,
    float* __restrict__ out, int n)
{
    __shared__ float sW[DIN * HDIM];
    __shared__ float sb[HDIM];
    int bf = flag[0];
    const void* W = bf ? wb : wf;
    const void* b = bf ? bb : bfp;
    const void* feat = bf ? fb : ff;
    int tid = threadIdx.x;
    for (int k = tid; k < DIN * HDIM; k += 256) sW[k] = ldf(W, k, bf);
    if (tid < HDIM) sb[tid] = ldf(b, tid, bf);
    __syncthreads();
    int node = blockIdx.x * 4 + (tid >> 6);
    if (node >= n) return;
    int h = tid & 63;
    float acc = sb[h];
    #pragma unroll
    for (int d = 0; d < DIN; ++d)
        acc += ldf(feat, (size_t)node * DIN + d, bf) * sW[d * HDIM + h];
    out[(size_t)node * HDIM + h] = acc;
}

__global__ __launch_bounds__(256) void lin_d64_kernel(
    const float* __restrict__ feat, const void* wb, const void* wf,
    const void* bb, const void* bfp, const int* __restrict__ flag,
    float* __restrict__ out, int n)
{
    __shared__ float sW[HDIM * HDIM];
    __shared__ float sb[HDIM];
    int bf = flag[0];
    const void* W = bf ? wb : wf;
    const void* b = bf ? bb : bfp;
    int tid = threadIdx.x;
    for (int k = tid; k < HDIM * HDIM; k += 256) sW[k] = ldf(W, k, bf);
    if (tid < HDIM) sb[tid] = ldf(b, tid, bf);
    __syncthreads();
    int node = blockIdx.x * 4 + (tid >> 6);
    if (node >= n) return;
    int h = tid & 63;
    float acc = sb[h];
    const float4* f4 = (const float4*)(feat + (size_t)node * HDIM);
    #pragma unroll
    for (int k = 0; k < 16; ++k) {
        float4 a = f4[k];
        acc += a.x * sW[(4*k+0) * HDIM + h] + a.y * sW[(4*k+1) * HDIM + h]
             + a.z * sW[(4*k+2) * HDIM + h] + a.w * sW[(4*k+3) * HDIM + h];
    }
    out[(size_t)node * HDIM + h] = acc;
}

// ---------------- fused GATv2 attention: one wave per dst node ----------------
// lane = feature h. Chunked (64 edges) online softmax entirely in registers:
// sweep 1 computes e_j (per-edge wave reduce) into lane-j register, sweep 2
// accumulates exp(e_j - m) * xl[src_j][h]. Single non-atomic output add.
__global__ __launch_bounds__(256) void gat_row_kernel(
    const int* __restrict__ rowptr, const int* __restrict__ col_src,
    const float* __restrict__ xl, const float* __restrict__ xr,
    const void* ab, const void* af, const int* __restrict__ flag,
    float* __restrict__ hn)
{
    int bf = flag[0];
    const void* att = bf ? ab : af;
    int wave = threadIdx.x >> 6;
    int lane = threadIdx.x & 63;
    int d = blockIdx.x * 4 + wave;
    if (d >= N_NODES) return;
    int rs = rowptr[d], re = rowptr[d + 1];
    if (re <= rs) return;

    float att_h = ldf(att, lane, bf);
    float xr_h = xr[(size_t)d * HDIM + lane];

    float m = -1e30f, s = 0.f, acc = 0.f;
    for (int cs = rs; cs < re; cs += 64) {
        int cnt = min(64, re - cs);
        int src_lane = (lane < cnt) ? col_src[cs + lane] : 0;
        float e_reg = -1e30f;
        for (int j = 0; j < cnt; ++j) {
            int src_j = __shfl(src_lane, j, 64);
            float v = xl[(size_t)src_j * HDIM + lane] + xr_h;
            v = v > 0.f ? v : 0.2f * v;
            float t = att_h * v;
            #pragma unroll
            for (int o = 32; o > 0; o >>= 1) t += __shfl_xor(t, o, 64);
            if (lane == j) e_reg = t;
        }
        float cm = e_reg;
        #pragma unroll
        for (int o = 32; o > 0; o >>= 1) cm = fmaxf(cm, __shfl_xor(cm, o, 64));
        if (cm > m) {
            float scale = __expf(m - cm);   // m=-1e30 first time -> 0, s/acc already 0
            s *= scale; acc *= scale; m = cm;
        }
        for (int j = 0; j < cnt; ++j) {
            float ej = __shfl(e_reg, j, 64);
            float w = __expf(ej - m);
            s += w;
            int src_j = __shfl(src_lane, j, 64);
            acc += w * xl[(size_t)src_j * HDIM + lane];
        }
    }
    hn[(size_t)d * HDIM + lane] += acc / (s + 1e-16f);
}

// ---------------- epilogue ----------------

__global__ void bsum_kernel(const void* __restrict__ bias, const int* __restrict__ flag,
                            float* __restrict__ bsum)
{
    int bf = flag[0];
    int idx = threadIdx.x;  // 192 = 3*64
    if (idx >= 192) return;
    int nt = idx >> 6, h = idx & 63;
    float v;
    if (nt == 0)      v = ldf(bias, 0*64+h, bf) + ldf(bias, 1*64+h, bf) + ldf(bias, 4*64+h, bf);
    else if (nt == 1) v = ldf(bias, 2*64+h, bf) + ldf(bias, 5*64+h, bf);
    else              v = ldf(bias, 3*64+h, bf) + ldf(bias, 6*64+h, bf);
    bsum[idx] = v;
}

__global__ __launch_bounds__(256) void relu_kernel(
    const float* __restrict__ hn, const float* __restrict__ bsum,
    float* __restrict__ h)
{
    size_t idx = (size_t)blockIdx.x * 256 + threadIdx.x;
    if (idx >= (size_t)3 * N_NODES * HDIM) return;
    int nt = (int)(idx / ((size_t)N_NODES * HDIM));
    int hh = (int)(idx & 63);
    float v = hn[idx] + bsum[nt * 64 + hh];
    h[idx] = v > 0.f ? v : 0.f;
}

__global__ __launch_bounds__(256) void head_kernel(
    const float* __restrict__ h0, const void* __restrict__ Wout,
    const void* __restrict__ bout, const int* __restrict__ flag,
    void* __restrict__ out)
{
    __shared__ float sW[64 * 4];
    __shared__ float sb[4];
    int bf = flag[0];
    int tid = threadIdx.x;
    sW[tid] = ldf(Wout, tid, bf);
    if (tid < 4) sb[tid] = ldf(bout, tid, bf);
    __syncthreads();
    int i = blockIdx.x * 256 + tid;
    if (i >= N_NODES) return;
    float l0 = sb[0], l1 = sb[1], l2 = sb[2], l3 = sb[3];
    const float4* p = (const float4*)(h0 + (size_t)i * HDIM);
    #pragma unroll
    for (int k = 0; k < 16; ++k) {
        float4 a = p[k];
        int d = 4 * k;
        l0 += a.x * sW[d*4+0] + a.y * sW[(d+1)*4+0] + a.z * sW[(d+2)*4+0] + a.w * sW[(d+3)*4+0];
        l1 += a.x * sW[d*4+1] + a.y * sW[(d+1)*4+1] + a.z * sW[(d+2)*4+1] + a.w * sW[(d+3)*4+1];
        l2 += a.x * sW[d*4+2] + a.y * sW[(d+1)*4+2] + a.z * sW[(d+2)*4+2] + a.w * sW[(d+3)*4+2];
        l3 += a.x * sW[d*4+3] + a.y * sW[(d+1)*4+3] + a.z * sW[(d+2)*4+3] + a.w * sW[(d+3)*4+3];
    }
    float m = fmaxf(fmaxf(l0, l1), fmaxf(l2, l3));
    float e0 = __expf(l0 - m), e1 = __expf(l1 - m), e2 = __expf(l2 - m), e3 = __expf(l3 - m);
    float inv = 1.f / (e0 + e1 + e2 + e3);
    if (bf) {
        bf16* o = (bf16*)out;
        o[(size_t)4*i + 0] = __float2bfloat16(e0 * inv);
        o[(size_t)4*i + 1] = __float2bfloat16(e1 * inv);
        o[(size_t)4*i + 2] = __float2bfloat16(e2 * inv);
        o[(size_t)4*i + 3] = __float2bfloat16(e3 * inv);
    } else {
        float* o = (float*)out;
        o[(size_t)4*i + 0] = e0 * inv;
        o[(size_t)4*i + 1] = e1 * inv;
        o[(size_t)4*i + 2] = e2 * inv;
        o[(size_t)4*i + 3] = e3 * inv;
    }
}

struct P2 { const void* b; const void* f; };
static inline P2 off2(const void* base, size_t elem) {
    P2 r;
    r.b = (const void*)((const bf16*)base + elem);
    r.f = (const void*)((const float*)base + elem);
    return r;
}

extern "C" void kernel_launch(void* const* d_in, const int* in_sizes, int n_in,
                              void* d_out, int out_size, void* d_ws, size_t ws_size,
                              hipStream_t stream)
{
    const void* x     = d_in[0];
    const int*  edges = (const int*)d_in[1];
    const void* Wl0 = d_in[2];
    const void* Wr0 = d_in[3];
    const void* bl0 = d_in[4];
    const void* br0 = d_in[5];
    const void* att0 = d_in[6];
    const void* bias0 = d_in[7];
    const void* Wl1 = d_in[8];
    const void* Wr1 = d_in[9];
    const void* bl1 = d_in[10];
    const void* br1 = d_in[11];
    const void* att1 = d_in[12];
    const void* bias1 = d_in[13];
    const void* Wout = d_in[14];
    const void* bout = d_in[15];

    const int SRCt[7] = {0, 1, 1, 1, 2, 2, 2};
    const int DSTt[7] = {0, 0, 1, 2, 0, 1, 2};

    // workspace layout (~106.3 MB, same budget as the proven R2 layout)
    float* h3   = (float*)d_ws;                                 // 3*N*H
    float* hn3  = h3 + (size_t)3 * N_NODES * HDIM;              // 3*N*H
    float* xl   = hn3 + (size_t)3 * N_NODES * HDIM;             // N*H
    float* xr   = xl + (size_t)N_NODES * HDIM;                  // N*H
    int* cnt     = (int*)(xr + (size_t)N_NODES * HDIM);         // N
    int* rowptr  = cnt + N_NODES;                               // N+1
    int* cursor  = rowptr + (N_NODES + 1);                      // N
    int* col_src = cursor + N_NODES;                            // E
    float* bsum  = (float*)(col_src + NEDGE);                   // 192
    int* flag    = (int*)(bsum + 192);                          // 1

    dim3 blk(256);
    int gLin  = (N_NODES + 3) / 4;
    int gE    = (NEDGE + 255) / 256;
    int gRow  = (N_NODES + 3) / 4;
    int gRelu = (int)(((size_t)3 * N_NODES * HDIM + 255) / 256);
    int gHead = (N_NODES + 255) / 256;

    detect_kernel<<<1, 256, 0, stream>>>((const unsigned short*)x, flag);

    for (int layer = 0; layer < 2; ++layer) {
        const void* Wl = layer ? Wl1 : Wl0;
        const void* Wr = layer ? Wr1 : Wr0;
        const void* bl = layer ? bl1 : bl0;
        const void* br = layer ? br1 : br0;
        const void* at = layer ? att1 : att0;
        const void* bi = layer ? bias1 : bias0;

        hipMemsetAsync(hn3, 0, (size_t)3 * N_NODES * HDIM * sizeof(float), stream);
        bsum_kernel<<<1, 192, 0, stream>>>(bi, flag, bsum);

        for (int t = 0; t < 7; ++t) {
            const int* ei = edges + (size_t)t * 2 * NEDGE;

            // CSR build for this edge type (dst-major)
            hipMemsetAsync(cnt, 0, N_NODES * sizeof(int), stream);
            hist_kernel<<<gE, blk, 0, stream>>>(ei + NEDGE, cnt);
            scan_kernel<<<1, 1024, 0, stream>>>(cnt, rowptr, cursor);
            scatter_kernel<<<gE, blk, 0, stream>>>(ei, cursor, col_src);

            // xl = src-type feats @ Wl[t] + bl[t];  xr = dst-type feats @ Wr[t] + br[t]
            if (layer == 0) {
                P2 fs = off2(x, (size_t)SRCt[t] * N_NODES * DIN);
                P2 fd = off2(x, (size_t)DSTt[t] * N_NODES * DIN);
                P2 wl = off2(Wl, (size_t)t * DIN * HDIM);
                P2 wr = off2(Wr, (size_t)t * DIN * HDIM);
                P2 bL = off2(bl, (size_t)t * HDIM);
                P2 bR = off2(br, (size_t)t * HDIM);
                lin_d32_kernel<<<gLin, blk, 0, stream>>>(fs.b, fs.f, wl.b, wl.f, bL.b, bL.f, flag, xl, N_NODES);
                lin_d32_kernel<<<gLin, blk, 0, stream>>>(fd.b, fd.f, wr.b, wr.f, bR.b, bR.f, flag, xr, N_NODES);
            } else {
                P2 wl = off2(Wl, (size_t)t * HDIM * HDIM);
                P2 wr = off2(Wr, (size_t)t * HDIM * HDIM);
                P2 bL = off2(bl, (size_t)t * HDIM);
                P2 bR = off2(br, (size_t)t * HDIM);
                lin_d64_kernel<<<gLin, blk, 0, stream>>>(h3 + (size_t)SRCt[t] * N_NODES * HDIM,
                                                         wl.b, wl.f, bL.b, bL.f, flag, xl, N_NODES);
                lin_d64_kernel<<<gLin, blk, 0, stream>>>(h3 + (size_t)DSTt[t] * N_NODES * HDIM,
                                                         wr.b, wr.f, bR.b, bR.f, flag, xr, N_NODES);
            }

            P2 a2 = off2(at, (size_t)t * HDIM);
            gat_row_kernel<<<gRow, blk, 0, stream>>>(rowptr, col_src, xl, xr,
                                                     a2.b, a2.f, flag,
                                                     hn3 + (size_t)DSTt[t] * N_NODES * HDIM);
        }
        relu_kernel<<<gRelu, blk, 0, stream>>>(hn3, bsum, h3);
    }

    head_kernel<<<gHead, blk, 0, stream>>>(h3, Wout, bout, flag, d_out);
}

// Round 4
// 3376.332 us; speedup vs baseline: 12.0314x; 1.6640x over previous
//
#include <hip/hip_runtime.h>
#include <hip/hip_bf16.h>

// HeteroGATv2: 3 node types x 50000 nodes, 7 edge types x 800000 edges,
// 2 GATv2 layers (H=64), softmax head (4 classes) on node type 0.
//
// R4: CSR built ONCE for all 7 edge types (edge structure is layer-invariant)
// with a multi-block 3-kernel scan (R3's single-block scan was 127us x14 =
// 32% of runtime at 0.15% occupancy). Runtime ws_size gate: if the 7-type
// CSR cache (~126 MB) doesn't fit, fall back to per-(layer,type) rebuild
// (~106 MB) still using the fast scan. Both paths deterministic.
//
// Dtype-adaptive (proven in R2): detector decides bf16 vs f32 once.

#define N_NODES 50000
#define NEDGE   800000
#define HDIM    64
#define DIN     32

typedef __hip_bfloat16 bf16;

__device__ __forceinline__ float ldf(const void* p, size_t i, int bf) {
    return bf ? __bfloat162float(((const bf16*)p)[i]) : ((const float*)p)[i];
}

// flag[0] = 1 if x is bf16, 0 if f32.
__global__ void detect_kernel(const unsigned short* __restrict__ x, int* __restrict__ flag)
{
    __shared__ int sbad[256];
    int bad = 0;
    for (int i = threadIdx.x; i < 4096; i += 256) {
        unsigned short u = x[i];
        int ex = (u >> 7) & 0xff;
        bool zero = (u & 0x7fffu) == 0;
        if (!zero && (ex < 80 || ex > 140)) bad++;
    }
    sbad[threadIdx.x] = bad;
    __syncthreads();
    for (int s = 128; s > 0; s >>= 1) {
        if (threadIdx.x < s) sbad[threadIdx.x] += sbad[threadIdx.x + s];
        __syncthreads();
    }
    if (threadIdx.x == 0) flag[0] = (sbad[0] < 64) ? 1 : 0;
}

// ---------------- batched CSR build ----------------
// Edge-global id g in [0, ntypes*E); t = g/E. Counters are cnt[t*N + dst].

__global__ __launch_bounds__(256) void hist_kernel(const int* __restrict__ edges,
                                                   int* __restrict__ cnt, int ntypes)
{
    int g = blockIdx.x * 256 + threadIdx.x;
    if (g >= ntypes * NEDGE) return;
    int t = g / NEDGE, i = g - t * NEDGE;
    int d = edges[(size_t)t * 2 * NEDGE + NEDGE + i];
    atomicAdd(&cnt[t * N_NODES + d], 1);
}

// scan stage A: per-block (2048 items) sums
__global__ __launch_bounds__(256) void scanA_kernel(const int* __restrict__ cnt,
                                                    int* __restrict__ bsums, int n)
{
    __shared__ int lds[256];
    int tid = threadIdx.x;
    int base = blockIdx.x * 2048 + tid * 8;
    int s = 0;
    #pragma unroll
    for (int k = 0; k < 8; ++k) { int i = base + k; if (i < n) s += cnt[i]; }
    lds[tid] = s;
    __syncthreads();
    for (int o = 128; o > 0; o >>= 1) {
        if (tid < o) lds[tid] += lds[tid + o];
        __syncthreads();
    }
    if (tid == 0) bsums[blockIdx.x] = lds[0];
}

// scan stage B: exclusive scan of block sums (nb <= 256); writes P[n] = total
__global__ __launch_bounds__(256) void scanB_kernel(const int* __restrict__ bsums,
                                                    int* __restrict__ boffs, int nb,
                                                    int* __restrict__ P, int n)
{
    __shared__ int lds[256];
    int tid = threadIdx.x;
    int v = (tid < nb) ? bsums[tid] : 0;
    lds[tid] = v;
    __syncthreads();
    for (int off = 1; off < 256; off <<= 1) {
        int t2 = (tid >= off) ? lds[tid - off] : 0;
        __syncthreads();
        lds[tid] += t2;
        __syncthreads();
    }
    if (tid < nb) boffs[tid] = lds[tid] - v;
    if (tid == 255) P[n] = lds[255];
}

// scan stage C: local exclusive scan + block offset -> P[i], cursor[i]
__global__ __launch_bounds__(256) void scanC_kernel(const int* __restrict__ cnt,
                                                    const int* __restrict__ boffs,
                                                    int* __restrict__ P,
                                                    int* __restrict__ cursor, int n)
{
    __shared__ int lds[256];
    int tid = threadIdx.x;
    int base = blockIdx.x * 2048 + tid * 8;
    int v[8];
    int s = 0;
    #pragma unroll
    for (int k = 0; k < 8; ++k) {
        int i = base + k;
        int c = (i < n) ? cnt[i] : 0;
        v[k] = s;
        s += c;
    }
    lds[tid] = s;
    __syncthreads();
    for (int off = 1; off < 256; off <<= 1) {
        int t2 = (tid >= off) ? lds[tid - off] : 0;
        __syncthreads();
        lds[tid] += t2;
        __syncthreads();
    }
    int off0 = boffs[blockIdx.x] + (lds[tid] - s);
    #pragma unroll
    for (int k = 0; k < 8; ++k) {
        int i = base + k;
        if (i < n) { int val = off0 + v[k]; P[i] = val; cursor[i] = val; }
    }
}

__global__ __launch_bounds__(256) void scatter_kernel(const int* __restrict__ edges,
                                                      int* __restrict__ cursor,
                                                      int* __restrict__ col_src, int ntypes)
{
    int g = blockIdx.x * 256 + threadIdx.x;
    if (g >= ntypes * NEDGE) return;
    int t = g / NEDGE, i = g - t * NEDGE;
    int s = edges[(size_t)t * 2 * NEDGE + i];
    int d = edges[(size_t)t * 2 * NEDGE + NEDGE + i];
    int pos = atomicAdd(&cursor[t * N_NODES + d], 1);
    col_src[pos] = s;
}

// ---------------- linear transforms ----------------

__global__ __launch_bounds__(256) void lin_d32_kernel(
    const void* fb, const void* ff, const void* wb, const void* wf,
    const void* bb, const void* bfp, const int* __restrict__ flag,
    float* __restrict__ out, int n)
{
    __shared__ float sW[DIN * HDIM];
    __shared__ float sb[HDIM];
    int bf = flag[0];
    const void* W = bf ? wb : wf;
    const void* b = bf ? bb : bfp;
    const void* feat = bf ? fb : ff;
    int tid = threadIdx.x;
    for (int k = tid; k < DIN * HDIM; k += 256) sW[k] = ldf(W, k, bf);
    if (tid < HDIM) sb[tid] = ldf(b, tid, bf);
    __syncthreads();
    int node = blockIdx.x * 4 + (tid >> 6);
    if (node >= n) return;
    int h = tid & 63;
    float acc = sb[h];
    #pragma unroll
    for (int d = 0; d < DIN; ++d)
        acc += ldf(feat, (size_t)node * DIN + d, bf) * sW[d * HDIM + h];
    out[(size_t)node * HDIM + h] = acc;
}

__global__ __launch_bounds__(256) void lin_d64_kernel(
    const float* __restrict__ feat, const void* wb, const void* wf,
    const void* bb, const void* bfp, const int* __restrict__ flag,
    float* __restrict__ out, int n)
{
    __shared__ float sW[HDIM * HDIM];
    __shared__ float sb[HDIM];
    int bf = flag[0];
    const void* W = bf ? wb : wf;
    const void* b = bf ? bb : bfp;
    int tid = threadIdx.x;
    for (int k = tid; k < HDIM * HDIM; k += 256) sW[k] = ldf(W, k, bf);
    if (tid < HDIM) sb[tid] = ldf(b, tid, bf);
    __syncthreads();
    int node = blockIdx.x * 4 + (tid >> 6);
    if (node >= n) return;
    int h = tid & 63;
    float acc = sb[h];
    const float4* f4 = (const float4*)(feat + (size_t)node * HDIM);
    #pragma unroll
    for (int k = 0; k < 16; ++k) {
        float4 a = f4[k];
        acc += a.x * sW[(4*k+0) * HDIM + h] + a.y * sW[(4*k+1) * HDIM + h]
             + a.z * sW[(4*k+2) * HDIM + h] + a.w * sW[(4*k+3) * HDIM + h];
    }
    out[(size_t)node * HDIM + h] = acc;
}

// ---------------- fused GATv2 attention: one wave per dst node ----------------
__global__ __launch_bounds__(256) void gat_row_kernel(
    const int* __restrict__ rowptr, const int* __restrict__ col_src,
    const float* __restrict__ xl, const float* __restrict__ xr,
    const void* ab, const void* af, const int* __restrict__ flag,
    float* __restrict__ hn)
{
    int bf = flag[0];
    const void* att = bf ? ab : af;
    int wave = threadIdx.x >> 6;
    int lane = threadIdx.x & 63;
    int d = blockIdx.x * 4 + wave;
    if (d >= N_NODES) return;
    int rs = rowptr[d], re = rowptr[d + 1];
    if (re <= rs) return;

    float att_h = ldf(att, lane, bf);
    float xr_h = xr[(size_t)d * HDIM + lane];

    float m = -1e30f, s = 0.f, acc = 0.f;
    for (int cs = rs; cs < re; cs += 64) {
        int cnt = min(64, re - cs);
        int src_lane = (lane < cnt) ? col_src[cs + lane] : 0;
        float e_reg = -1e30f;
        for (int j = 0; j < cnt; ++j) {
            int src_j = __shfl(src_lane, j, 64);
            float v = xl[(size_t)src_j * HDIM + lane] + xr_h;
            v = v > 0.f ? v : 0.2f * v;
            float t = att_h * v;
            #pragma unroll
            for (int o = 32; o > 0; o >>= 1) t += __shfl_xor(t, o, 64);
            if (lane == j) e_reg = t;
        }
        float cm = e_reg;
        #pragma unroll
        for (int o = 32; o > 0; o >>= 1) cm = fmaxf(cm, __shfl_xor(cm, o, 64));
        if (cm > m) {
            float scale = __expf(m - cm);
            s *= scale; acc *= scale; m = cm;
        }
        for (int j = 0; j < cnt; ++j) {
            float ej = __shfl(e_reg, j, 64);
            float w = __expf(ej - m);
            s += w;
            int src_j = __shfl(src_lane, j, 64);
            acc += w * xl[(size_t)src_j * HDIM + lane];
        }
    }
    hn[(size_t)d * HDIM + lane] += acc / (s + 1e-16f);
}

// ---------------- epilogue ----------------

__global__ void bsum_kernel(const void* __restrict__ bias, const int* __restrict__ flag,
                            float* __restrict__ bsum)
{
    int bf = flag[0];
    int idx = threadIdx.x;  // 192 = 3*64
    if (idx >= 192) return;
    int nt = idx >> 6, h = idx & 63;
    float v;
    if (nt == 0)      v = ldf(bias, 0*64+h, bf) + ldf(bias, 1*64+h, bf) + ldf(bias, 4*64+h, bf);
    else if (nt == 1) v = ldf(bias, 2*64+h, bf) + ldf(bias, 5*64+h, bf);
    else              v = ldf(bias, 3*64+h, bf) + ldf(bias, 6*64+h, bf);
    bsum[idx] = v;
}

__global__ __launch_bounds__(256) void relu_kernel(
    const float* __restrict__ hn, const float* __restrict__ bsum,
    float* __restrict__ h)
{
    size_t idx = (size_t)blockIdx.x * 256 + threadIdx.x;
    if (idx >= (size_t)3 * N_NODES * HDIM) return;
    int nt = (int)(idx / ((size_t)N_NODES * HDIM));
    int hh = (int)(idx & 63);
    float v = hn[idx] + bsum[nt * 64 + hh];
    h[idx] = v > 0.f ? v : 0.f;
}

__global__ __launch_bounds__(256) void head_kernel(
    const float* __restrict__ h0, const void* __restrict__ Wout,
    const void* __restrict__ bout, const int* __restrict__ flag,
    void* __restrict__ out)
{
    __shared__ float sW[64 * 4];
    __shared__ float sb[4];
    int bf = flag[0];
    int tid = threadIdx.x;
    sW[tid] = ldf(Wout, tid, bf);
    if (tid < 4) sb[tid] = ldf(bout, tid, bf);
    __syncthreads();
    int i = blockIdx.x * 256 + tid;
    if (i >= N_NODES) return;
    float l0 = sb[0], l1 = sb[1], l2 = sb[2], l3 = sb[3];
    const float4* p = (const float4*)(h0 + (size_t)i * HDIM);
    #pragma unroll
    for (int k = 0; k < 16; ++k) {
        float4 a = p[k];
        int d = 4 * k;
        l0 += a.x * sW[d*4+0] + a.y * sW[(d+1)*4+0] + a.z * sW[(d+2)*4+0] + a.w * sW[(d+3)*4+0];
        l1 += a.x * sW[d*4+1] + a.y * sW[(d+1)*4+1] + a.z * sW[(d+2)*4+1] + a.w * sW[(d+3)*4+1];
        l2 += a.x * sW[d*4+2] + a.y * sW[(d+1)*4+2] + a.z * sW[(d+2)*4+2] + a.w * sW[(d+3)*4+2];
        l3 += a.x * sW[d*4+3] + a.y * sW[(d+1)*4+3] + a.z * sW[(d+2)*4+3] + a.w * sW[(d+3)*4+3];
    }
    float m = fmaxf(fmaxf(l0, l1), fmaxf(l2, l3));
    float e0 = __expf(l0 - m), e1 = __expf(l1 - m), e2 = __expf(l2 - m), e3 = __expf(l3 - m);
    float inv = 1.f / (e0 + e1 + e2 + e3);
    if (bf) {
        bf16* o = (bf16*)out;
        o[(size_t)4*i + 0] = __float2bfloat16(e0 * inv);
        o[(size_t)4*i + 1] = __float2bfloat16(e1 * inv);
        o[(size_t)4*i + 2] = __float2bfloat16(e2 * inv);
        o[(size_t)4*i + 3] = __float2bfloat16(e3 * inv);
    } else {
        float* o = (float*)out;
        o[(size_t)4*i + 0] = e0 * inv;
        o[(size_t)4*i + 1] = e1 * inv;
        o[(size_t)4*i + 2] = e2 * inv;
        o[(size_t)4*i + 3] = e3 * inv;
    }
}

struct P2 { const void* b; const void* f; };
static inline P2 off2(const void* base, size_t elem) {
    P2 r;
    r.b = (const void*)((const bf16*)base + elem);
    r.f = (const void*)((const float*)base + elem);
    return r;
}

extern "C" void kernel_launch(void* const* d_in, const int* in_sizes, int n_in,
                              void* d_out, int out_size, void* d_ws, size_t ws_size,
                              hipStream_t stream)
{
    const void* x     = d_in[0];
    const int*  edges = (const int*)d_in[1];
    const void* Wl0 = d_in[2];
    const void* Wr0 = d_in[3];
    const void* bl0 = d_in[4];
    const void* br0 = d_in[5];
    const void* att0 = d_in[6];
    const void* bias0 = d_in[7];
    const void* Wl1 = d_in[8];
    const void* Wr1 = d_in[9];
    const void* bl1 = d_in[10];
    const void* br1 = d_in[11];
    const void* att1 = d_in[12];
    const void* bias1 = d_in[13];
    const void* Wout = d_in[14];
    const void* bout = d_in[15];

    const int SRCt[7] = {0, 1, 1, 1, 2, 2, 2};
    const int DSTt[7] = {0, 0, 1, 2, 0, 1, 2};

    // ---- workspace layout ----
    float* h3  = (float*)d_ws;                                  // 3*N*H
    float* hn3 = h3 + (size_t)3 * N_NODES * HDIM;               // 3*N*H
    float* xl  = hn3 + (size_t)3 * N_NODES * HDIM;              // N*H
    float* xr  = xl + (size_t)N_NODES * HDIM;                   // N*H
    char* tail = (char*)(xr + (size_t)N_NODES * HDIM);

    // full path: P[7N+1], col_src[7E]; fallback: P[N+1], col_src[E]
    size_t fixed = (size_t)tail - (size_t)d_ws;
    size_t need_full = fixed + ((size_t)7 * N_NODES + 1) * 4 + (size_t)7 * NEDGE * 4
                     + 2 * 256 * 4 + 192 * 4 + 4 + 2 * (size_t)N_NODES * 4 + 256;
    bool full = ws_size >= need_full;
    int NT = full ? 7 : 1;

    int* P        = (int*)tail;                                 // NT*N+1
    int* col_src  = P + ((size_t)NT * N_NODES + 1);             // NT*E
    int* bsums    = col_src + (size_t)NT * NEDGE;               // 256
    int* boffs    = bsums + 256;                                // 256
    float* bsum   = (float*)(boffs + 256);                      // 192
    int* flag     = (int*)(bsum + 192);                         // 1
    int* cnt;
    int* cursor;
    if (full) {
        // build precedes any hn3 use (stream-ordered) -> alias into hn3
        cnt = (int*)hn3;                                        // 7N
        cursor = cnt + (size_t)7 * N_NODES;                     // 7N
    } else {
        cnt = flag + 1;                                         // N
        cursor = cnt + N_NODES;                                 // N
    }

    dim3 blk(256);
    int gLin  = (N_NODES + 3) / 4;
    int gRow  = (N_NODES + 3) / 4;
    int gRelu = (int)(((size_t)3 * N_NODES * HDIM + 255) / 256);
    int gHead = (N_NODES + 255) / 256;

    detect_kernel<<<1, 256, 0, stream>>>((const unsigned short*)x, flag);

    if (full) {
        int n = 7 * N_NODES;
        int nb = (n + 2047) / 2048;                 // 171
        int gE7 = (7 * NEDGE + 255) / 256;
        hipMemsetAsync(cnt, 0, (size_t)n * sizeof(int), stream);
        hist_kernel<<<gE7, blk, 0, stream>>>(edges, cnt, 7);
        scanA_kernel<<<nb, blk, 0, stream>>>(cnt, bsums, n);
        scanB_kernel<<<1, blk, 0, stream>>>(bsums, boffs, nb, P, n);
        scanC_kernel<<<nb, blk, 0, stream>>>(cnt, boffs, P, cursor, n);
        scatter_kernel<<<gE7, blk, 0, stream>>>(edges, cursor, col_src, 7);
    }

    for (int layer = 0; layer < 2; ++layer) {
        const void* Wl = layer ? Wl1 : Wl0;
        const void* Wr = layer ? Wr1 : Wr0;
        const void* bl = layer ? bl1 : bl0;
        const void* br = layer ? br1 : br0;
        const void* at = layer ? att1 : att0;
        const void* bi = layer ? bias1 : bias0;

        hipMemsetAsync(hn3, 0, (size_t)3 * N_NODES * HDIM * sizeof(float), stream);
        bsum_kernel<<<1, 192, 0, stream>>>(bi, flag, bsum);

        for (int t = 0; t < 7; ++t) {
            const int* rp;
            const int* cs;
            if (full) {
                rp = P + (size_t)t * N_NODES;
                cs = col_src;    // P holds GLOBAL positions into col_src
            } else {
                const int* et = edges + (size_t)t * 2 * NEDGE;
                int n = N_NODES;
                int nb = (n + 2047) / 2048;         // 25
                int gE1 = (NEDGE + 255) / 256;
                hipMemsetAsync(cnt, 0, (size_t)n * sizeof(int), stream);
                hist_kernel<<<gE1, blk, 0, stream>>>(et, cnt, 1);
                scanA_kernel<<<nb, blk, 0, stream>>>(cnt, bsums, n);
                scanB_kernel<<<1, blk, 0, stream>>>(bsums, boffs, nb, P, n);
                scanC_kernel<<<nb, blk, 0, stream>>>(cnt, boffs, P, cursor, n);
                scatter_kernel<<<gE1, blk, 0, stream>>>(et, cursor, col_src, 1);
                rp = P;
                cs = col_src;
            }

            if (layer == 0) {
                P2 fs = off2(x, (size_t)SRCt[t] * N_NODES * DIN);
                P2 fd = off2(x, (size_t)DSTt[t] * N_NODES * DIN);
                P2 wl = off2(Wl, (size_t)t * DIN * HDIM);
                P2 wr = off2(Wr, (size_t)t * DIN * HDIM);
                P2 bL = off2(bl, (size_t)t * HDIM);
                P2 bR = off2(br, (size_t)t * HDIM);
                lin_d32_kernel<<<gLin, blk, 0, stream>>>(fs.b, fs.f, wl.b, wl.f, bL.b, bL.f, flag, xl, N_NODES);
                lin_d32_kernel<<<gLin, blk, 0, stream>>>(fd.b, fd.f, wr.b, wr.f, bR.b, bR.f, flag, xr, N_NODES);
            } else {
                P2 wl = off2(Wl, (size_t)t * HDIM * HDIM);
                P2 wr = off2(Wr, (size_t)t * HDIM * HDIM);
                P2 bL = off2(bl, (size_t)t * HDIM);
                P2 bR = off2(br, (size_t)t * HDIM);
                lin_d64_kernel<<<gLin, blk, 0, stream>>>(h3 + (size_t)SRCt[t] * N_NODES * HDIM,
                                                         wl.b, wl.f, bL.b, bL.f, flag, xl, N_NODES);
                lin_d64_kernel<<<gLin, blk, 0, stream>>>(h3 + (size_t)DSTt[t] * N_NODES * HDIM,
                                                         wr.b, wr.f, bR.b, bR.f, flag, xr, N_NODES);
            }

            P2 a2 = off2(at, (size_t)t * HDIM);
            gat_row_kernel<<<gRow, blk, 0, stream>>>(rp, cs, xl, xr,
                                                     a2.b, a2.f, flag,
                                                     hn3 + (size_t)DSTt[t] * N_NODES * HDIM);
        }
        relu_kernel<<<gRelu, blk, 0, stream>>>(hn3, bsum, h3);
    }

    head_kernel<<<gHead, blk, 0, stream>>>(h3, Wout, bout, flag, d_out);
}